// Round 12
// baseline (472.310 us; speedup 1.0000x reference)
//
#include <hip/hip_runtime.h>

// ---------------------------------------------------------------------------
// Generator head, fused:
//   FC(1024->7056) + reshape + Conv2x2'same' folded into one bf16 GEMM
//   (M=8192, N=3136 pad 3200, K=1024), epilogue = +bias, LeakyReLU, bf16 out
//   + fused per-channel BN statistics (sum/sumsq) via block reduce + atomics.
//   Then BN-apply + 2 locally-connected convs.
// ---------------------------------------------------------------------------

#define SLOPE 0.01f

typedef __bf16 bf16x8 __attribute__((ext_vector_type(8)));
typedef float f32x4 __attribute__((ext_vector_type(4)));

typedef const __attribute__((address_space(1))) void* gas_ptr;
typedef __attribute__((address_space(3))) void* las_ptr;

__device__ __forceinline__ void load16_to_lds(const void* g, void* l) {
  __builtin_amdgcn_global_load_lds((gas_ptr)g, (las_ptr)l, 16, 0, 0);
}

__device__ __forceinline__ unsigned short f2bf(float f) {
  union { float f; unsigned int u; } v; v.f = f;
  unsigned int r = v.u + 0x7FFFu + ((v.u >> 16) & 1u);
  return (unsigned short)(r >> 16);
}
__device__ __forceinline__ float bfbits2f(unsigned int bits16) {
  union { unsigned int u; float f; } v; v.u = bits16 << 16;
  return v.f;
}
__device__ __forceinline__ float leaky(float v) { return v >= 0.f ? v : SLOPE * v; }

// ---------------- K0+K1 fused: cast x to bf16  AND  fold conv into fc ------
// blocks [0,4096): cast 8.4M floats (8/thread).
// blocks [4096,4884): fold, r = bid-4096, blk = r%197, kg = r/197.
//   Wc row n = o*196 + i*14 + j, K=1024; rows [3136,3200) zero.
__global__ void k_prep(const float* __restrict__ x, unsigned short* __restrict__ xb,
                       const float* __restrict__ fc_w, const float* __restrict__ fc_b,
                       const float* __restrict__ conv_w, const float* __restrict__ conv_b,
                       unsigned short* __restrict__ Wc, float* __restrict__ bc,
                       float* __restrict__ stats) {
  __shared__ float cw[2304];  // fold path only (16*36*2*2)
  const int bid = blockIdx.x, t = threadIdx.x;
  if (bid < 4096) {           // ---- cast path ----
    if (bid == 0 && t < 32) stats[t] = 0.f;  // zero BN accumulators
    int gid = bid * 256 + t;
    const float4* x4 = (const float4*)x;
    float4 a = x4[gid * 2], b = x4[gid * 2 + 1];
    union { unsigned short s[8]; uint4 v; } o;
    o.s[0] = f2bf(a.x); o.s[1] = f2bf(a.y); o.s[2] = f2bf(a.z); o.s[3] = f2bf(a.w);
    o.s[4] = f2bf(b.x); o.s[5] = f2bf(b.y); o.s[6] = f2bf(b.z); o.s[7] = f2bf(b.w);
    ((uint4*)xb)[gid] = o.v;
    return;
  }
  // ---- fold path ----
  const int r = bid - 4096;
  const int blk = r % 197, kg = r / 197;
  if (blk == 196) {  // zero pad rows (one copy of this work only)
    if (kg != 0) return;
    uint4 z = make_uint4(0, 0, 0, 0);
    uint4* dst = (uint4*)(Wc + 3136 * 1024);
    for (int i = t; i < 8192; i += 256) dst[i] = z;   // 64 rows * 2048 B
    for (int i = 3136 + t; i < 3200; i += 256) bc[i] = 0.f;
    return;
  }
  for (int i = t; i < 2304; i += 256) cw[i] = conv_w[i];
  __syncthreads();
  int i0 = blk / 14, j0 = blk - (blk / 14) * 14;
  int kcol = kg * 256 + t;
  float acc[16];
#pragma unroll
  for (int o = 0; o < 16; o++) acc[o] = 0.f;
  for (int c = 0; c < 36; c++) {
#pragma unroll
    for (int dy = 0; dy < 2; dy++) {
      int ii = i0 + dy; if (ii > 13) continue;
#pragma unroll
      for (int dx = 0; dx < 2; dx++) {
        int jj = j0 + dx; if (jj > 13) continue;
        int row = (ii * 14 + jj) * 36 + c;
        float f = fc_w[row * 1024 + kcol];
        int kk = dy * 2 + dx;
#pragma unroll
        for (int o = 0; o < 16; o++)
          acc[o] += cw[(o * 36 + c) * 4 + kk] * f;
      }
    }
  }
#pragma unroll
  for (int o = 0; o < 16; o++) {
    int n = o * 196 + i0 * 14 + j0;
    Wc[n * 1024 + kcol] = f2bf(acc[o]);
  }
  if (kg == 0 && t < 16) {
    int o = t;
    float b = conv_b[o];
    for (int c = 0; c < 36; c++)
      for (int dy = 0; dy < 2; dy++) {
        int ii = i0 + dy; if (ii > 13) continue;
        for (int dx = 0; dx < 2; dx++) {
          int jj = j0 + dx; if (jj > 13) continue;
          b += cw[(o * 36 + c) * 4 + dy * 2 + dx] * fc_b[(ii * 14 + jj) * 36 + c];
        }
      }
    bc[o * 196 + i0 * 14 + j0] = b;
  }
}

// --------------------------- K2: bf16 MFMA GEMM ----------------------------
// Frozen at the measured-best configuration (r5/r8: 139.2/139.0 µs):
// 128x128 tile, BK=32, 4 waves, plain 2-barrier single-buffer loop,
// XCD-bijective swizzle, fused BN stats. All scheduling variants measured
// worse or neutral (drain-0 dbuf r3, BK=64 r6, 256² r4/r9, counted-vmcnt r11).
__global__ __launch_bounds__(256, 4) void k_gemm(const unsigned short* __restrict__ Xb,
                                                 const unsigned short* __restrict__ Wcb,
                                                 const float* __restrict__ bc,
                                                 unsigned short* __restrict__ h2,
                                                 float* __restrict__ stats) {
  __shared__ __align__(16) char lds[16384];  // A: [0,8K), B: [8K,16K)
  __shared__ float red[4][4];
  const int t = threadIdx.x;
  const int w = t >> 6, lane = t & 63;
  const int quad = lane >> 4, l15 = lane & 15;
  // XCD-bijective swizzle: bid <-> (xcd, mloc, nblk); 1600 = 8 x 8 x 25
  const int bid = blockIdx.x;
  const int xcd = bid & 7, j = bid >> 3;       // j in [0,200)
  const int mblk = xcd * 8 + (j & 7);          // [0,64)
  const int nblk = j >> 3;                     // [0,25)
  const int m0 = mblk * 128, n0 = nblk * 128;
  const int mrow = t & 127, tko = t >> 7;      // staging: row in tile, base ko
  const unsigned short* ga = Xb + (m0 + mrow) * 1024 + tko * 8;
  const unsigned short* gb = Wcb + (n0 + mrow) * 1024 + tko * 8;
  char* lA = lds;
  char* lB = lds + 8192;
  const int wbase = w * 1024;
  const int wm0 = (w >> 1) * 64, wn0 = (w & 1) * 64;

  f32x4 acc[4][4];
#pragma unroll
  for (int a = 0; a < 4; a++)
#pragma unroll
    for (int b = 0; b < 4; b++) acc[a][b] = (f32x4){0.f, 0.f, 0.f, 0.f};

  for (int kb = 0; kb < 1024; kb += 32) {
    __syncthreads();
    load16_to_lds(ga + kb,      lA + wbase);           // A slots ko = tko
    load16_to_lds(ga + kb + 16, lA + 4096 + wbase);    // A slots ko = 2+tko
    load16_to_lds(gb + kb,      lB + wbase);
    load16_to_lds(gb + kb + 16, lB + 4096 + wbase);
    __syncthreads();  // compiler emits s_waitcnt vmcnt(0) before s_barrier

    bf16x8 af[4], bfr[4];
#pragma unroll
    for (int mb = 0; mb < 4; mb++)
      af[mb] = *(const bf16x8*)(lA + quad * 2048 + (wm0 + mb * 16 + l15) * 16);
#pragma unroll
    for (int nb = 0; nb < 4; nb++)
      bfr[nb] = *(const bf16x8*)(lB + quad * 2048 + (wn0 + nb * 16 + l15) * 16);
#pragma unroll
    for (int mb = 0; mb < 4; mb++)
#pragma unroll
      for (int nb = 0; nb < 4; nb++)
        acc[mb][nb] = __builtin_amdgcn_mfma_f32_16x16x32_bf16(af[mb], bfr[nb], acc[mb][nb], 0, 0, 0);
  }

  // ---- epilogue: bias + leaky + bf16 store + fused BN partial sums ----
  const int cLo = n0 / 196;              // block spans channels cLo..cHi (cHi<=cLo+1)
  const int cHi = (n0 + 127) / 196;      // may be 16 for the padded tail block
  float ss0 = 0.f, ss1 = 0.f, sq0 = 0.f, sq1 = 0.f;
#pragma unroll
  for (int nb = 0; nb < 4; nb++) {
    int col = n0 + wn0 + nb * 16 + l15;
    float bias = bc[col];
    int ch = col / 196;
    bool hi = (ch != cLo);
    bool valid = col < 3136;
    float cs = 0.f, cq = 0.f;
#pragma unroll
    for (int mb = 0; mb < 4; mb++) {
#pragma unroll
      for (int r = 0; r < 4; r++) {
        int row = m0 + wm0 + mb * 16 + quad * 4 + r;  // C/D: row=(lane>>4)*4+reg, col=lane&15
        float v = leaky(acc[mb][nb][r] + bias);
        h2[row * 3200 + col] = f2bf(v);
        cs += v; cq += v * v;
      }
    }
    if (valid) {
      if (hi) { ss1 += cs; sq1 += cq; } else { ss0 += cs; sq0 += cq; }
    }
  }
#pragma unroll
  for (int off = 1; off < 64; off <<= 1) {
    ss0 += __shfl_xor(ss0, off, 64);
    ss1 += __shfl_xor(ss1, off, 64);
    sq0 += __shfl_xor(sq0, off, 64);
    sq1 += __shfl_xor(sq1, off, 64);
  }
  if (lane == 0) { red[w][0] = ss0; red[w][1] = ss1; red[w][2] = sq0; red[w][3] = sq1; }
  __syncthreads();
  if (t == 0) {
    float a0 = red[0][0] + red[1][0] + red[2][0] + red[3][0];
    float a1 = red[0][1] + red[1][1] + red[2][1] + red[3][1];
    float b0 = red[0][2] + red[1][2] + red[2][2] + red[3][2];
    float b1 = red[0][3] + red[1][3] + red[2][3] + red[3][3];
    atomicAdd(&stats[cLo], a0);
    atomicAdd(&stats[16 + cLo], b0);
    if (cHi != cLo && cHi < 16) {
      atomicAdd(&stats[cHi], a1);
      atomicAdd(&stats[16 + cHi], b1);
    }
  }
}

// ------------- K4: BN-apply + local conv1 + leaky + local conv2 ------------
// Occupancy-first redesign: the old h3 LDS stage (25 KB) capped the kernel at
// 3 blocks/CU — for a gather-latency-bound kernel, occupancy IS the lever
// (weight-traffic cuts r6-r8 were all neutral). h2 is L2/L3-hot (written by
// k_gemm moments earlier), so conv1 reads it DIRECTLY from global with BN
// applied on the fly (2 extra FMA/elem). LDS = h4 (16.2 KB) + sc/sh only
// -> ~6 blocks/CU (launch_bounds(256,6) caps VGPR), 2048 blocks in ~1
// residency round instead of 2.7. Row-pairing dropped (reg-heavy, neutral).
__global__ __launch_bounds__(256, 6) void k_tail(const unsigned short* __restrict__ h2,
                                                 const float* __restrict__ stats,
                                                 const float* __restrict__ gamma,
                                                 const float* __restrict__ beta,
                                                 const float* __restrict__ lw1,
                                                 const float* __restrict__ lw2,
                                                 float* __restrict__ out) {
  __shared__ float h4[4 * 1015];           // bb stride 1015
  __shared__ float sc[16], sh[16];
  int b0 = blockIdx.x * 4, t = threadIdx.x;
  if (t < 16) {
    const float inv = 1.f / 1605632.f;  // 8192*196
    float mean = stats[t] * inv;
    float var = stats[16 + t] * inv - mean * mean;
    float rstd = rsqrtf(var + 1e-5f);
    float s = gamma[t] * rstd;
    sc[t] = s; sh[t] = beta[t] - mean * s;
  }
  __syncthreads();
  // local conv 1: unit = (bb, o, y); reads h2 rows y,y+1 per channel straight
  // from global (L2-hot), BN in registers. 312 units over 256 threads.
  for (int u = t; u < 312; u += 256) {
    int bb = u & 3, rest = u >> 2;
    int o = rest / 13, y = rest - o * 13;
    float acc[13];
#pragma unroll
    for (int x = 0; x < 13; x++) acc[x] = 0.f;
    const unsigned short* hb = h2 + (b0 + bb) * 3200;
    for (int c = 0; c < 16; c++) {
      float s = sc[c], h = sh[c];
      float r0[14], r1[14];
      const unsigned int* p0 = (const unsigned int*)(hb + c * 196 + y * 14);
      const unsigned int* p1 = (const unsigned int*)(hb + c * 196 + (y + 1) * 14);
#pragma unroll
      for (int q = 0; q < 7; q++) {
        unsigned int v0 = p0[q], v1 = p1[q];
        r0[2 * q]     = bfbits2f(v0 & 0xffffu) * s + h;
        r0[2 * q + 1] = bfbits2f(v0 >> 16) * s + h;
        r1[2 * q]     = bfbits2f(v1 & 0xffffu) * s + h;
        r1[2 * q + 1] = bfbits2f(v1 >> 16) * s + h;
      }
      const float4* wp4 = (const float4*)(lw1 + (((o * 16 + c) * 13 + y) * 13) * 4);
#pragma unroll
      for (int x = 0; x < 13; x++) {
        float4 wv = wp4[x];
        acc[x] += r0[x] * wv.x + r0[x + 1] * wv.y +
                  r1[x] * wv.z + r1[x + 1] * wv.w;
      }
    }
#pragma unroll
    for (int x = 0; x < 13; x++)
      h4[bb * 1015 + (o * 13 + y) * 13 + x] = leaky(acc[x]);
  }
  __syncthreads();
  // local conv 2: 4*144 outputs, 24 MACs each (float4 weights)
  for (int oi = t; oi < 576; oi += 256) {
    int pos = oi >> 2, bb = oi & 3;
    int y = pos / 12, x = pos - y * 12;
    float a = 0.f;
    const float* hp = h4 + bb * 1015;
    const float4* w4 = (const float4*)lw2;
#pragma unroll
    for (int c = 0; c < 6; c++) {
      float4 wv = w4[(c * 12 + y) * 12 + x];
      int hb = c * 169 + y * 13 + x;
      a += hp[hb] * wv.x + hp[hb + 1] * wv.y +
           hp[hb + 13] * wv.z + hp[hb + 14] * wv.w;
    }
    out[(b0 + bb) * 144 + pos] = a;
  }
}

// ---------------------------------------------------------------------------
extern "C" void kernel_launch(void* const* d_in, const int* in_sizes, int n_in,
                              void* d_out, int out_size, void* d_ws, size_t ws_size,
                              hipStream_t stream) {
  const float* x      = (const float*)d_in[0];
  const float* fc_w   = (const float*)d_in[1];
  const float* fc_b   = (const float*)d_in[2];
  const float* conv_w = (const float*)d_in[3];
  const float* conv_b = (const float*)d_in[4];
  const float* gamma  = (const float*)d_in[5];
  const float* beta   = (const float*)d_in[6];
  const float* lw1    = (const float*)d_in[7];
  const float* lw2    = (const float*)d_in[8];

  char* ws = (char*)d_ws;
  // workspace layout (75.8 MB total)
  unsigned short* Xb    = (unsigned short*)(ws);                // 16,777,216 B
  unsigned short* Wc    = (unsigned short*)(ws + 16777216);     //  6,553,600 B
  float*          bc    = (float*)(ws + 23330816);              //     12,800 B
  float*          stats = (float*)(ws + 23343616);              //        128 B
  unsigned short* h2    = (unsigned short*)(ws + 23343744);     // 52,428,800 B

  k_prep<<<4884, 256, 0, stream>>>(x, Xb, fc_w, fc_b, conv_w, conv_b, Wc, bc, stats);
  k_gemm<<<1600, 256, 0, stream>>>(Xb, Wc, bc, h2, stats);
  k_tail<<<2048, 256, 0, stream>>>(h2, stats, gamma, beta, lw1, lw2, (float*)d_out);
}

// Round 13
// 368.097 us; speedup vs baseline: 1.2831x; 1.2831x over previous
//
#include <hip/hip_runtime.h>

// ---------------------------------------------------------------------------
// Generator head, fused:
//   FC(1024->7056) + reshape + Conv2x2'same' folded into one bf16 GEMM
//   (M=8192, N=3136 pad 3200, K=1024), epilogue = +bias, LeakyReLU, bf16 out
//   + fused per-channel BN statistics (sum/sumsq) via block reduce + atomics.
//   Then BN-apply + 2 locally-connected convs.
// ---------------------------------------------------------------------------

#define SLOPE 0.01f

typedef __bf16 bf16x8 __attribute__((ext_vector_type(8)));
typedef float f32x4 __attribute__((ext_vector_type(4)));

typedef const __attribute__((address_space(1))) void* gas_ptr;
typedef __attribute__((address_space(3))) void* las_ptr;

__device__ __forceinline__ void load16_to_lds(const void* g, void* l) {
  __builtin_amdgcn_global_load_lds((gas_ptr)g, (las_ptr)l, 16, 0, 0);
}

__device__ __forceinline__ unsigned short f2bf(float f) {
  union { float f; unsigned int u; } v; v.f = f;
  unsigned int r = v.u + 0x7FFFu + ((v.u >> 16) & 1u);
  return (unsigned short)(r >> 16);
}
__device__ __forceinline__ float bfbits2f(unsigned int bits16) {
  union { unsigned int u; float f; } v; v.u = bits16 << 16;
  return v.f;
}
__device__ __forceinline__ float leaky(float v) { return v >= 0.f ? v : SLOPE * v; }

// --------------------------- K0: cast x to bf16 ----------------------------
__global__ void k_cast_x(const float* __restrict__ x, unsigned short* __restrict__ xb,
                         float* __restrict__ stats) {
  if (blockIdx.x == 0 && threadIdx.x < 32) stats[threadIdx.x] = 0.f;  // zero BN accumulators
  int gid = blockIdx.x * 256 + threadIdx.x;             // 8.4M floats / 8 per thread
  const float4* x4 = (const float4*)x;
  float4 a = x4[gid * 2], b = x4[gid * 2 + 1];
  union { unsigned short s[8]; uint4 v; } o;
  o.s[0] = f2bf(a.x); o.s[1] = f2bf(a.y); o.s[2] = f2bf(a.z); o.s[3] = f2bf(a.w);
  o.s[4] = f2bf(b.x); o.s[5] = f2bf(b.y); o.s[6] = f2bf(b.z); o.s[7] = f2bf(b.w);
  ((uint4*)xb)[gid] = o.v;
}

// ------------------- K1: fold conv into fc -> Wc (bf16), bc ----------------
// Wc row n = o*196 + i*14 + j (o<16, i<14, j<14), K=1024; rows [3136,3200) zero.
// LDS-throughput redesign: the old per-kcol-thread structure did 2304
// broadcast ds_read_b32 of weights PER THREAD (~54K LDS cyc/block) — that,
// not global latency, was the ~135 µs (r12 subtraction). Now each thread
// owns a float4 of kcols (one weight read serves 4 FMAs) and weights are
// read as float4 (576 ds_read_b128/thread, ~27.6K LDS cyc/block; VALU 18.4K).
// Boundary masks are folded into the LDS weight copy (cwm = conv_w * m[kk])
// with row bases clamped to valid memory -> branch-free inner loop.
__global__ void k_fold(const float* __restrict__ fc_w, const float* __restrict__ fc_b,
                       const float* __restrict__ conv_w, const float* __restrict__ conv_b,
                       unsigned short* __restrict__ Wc, float* __restrict__ bc) {
  __shared__ __align__(16) float cwm[2304];  // 16*36*2*2, boundary-masked
  int blk = blockIdx.x, t = threadIdx.x;
  if (blk == 196) {  // zero pad rows
    uint4 z = make_uint4(0, 0, 0, 0);
    uint4* dst = (uint4*)(Wc + 3136 * 1024);
    for (int i = t; i < 8192; i += 256) dst[i] = z;   // 64 rows * 2048 B
    for (int i = 3136 + t; i < 3200; i += 256) bc[i] = 0.f;
    return;
  }
  int i0 = blk / 14, j0 = blk - (blk / 14) * 14;
  // block-uniform masks + clamped row bases (clamped rows are valid memory;
  // their contribution is zeroed through the masked weights)
  float m[4];
  int rb[4];
#pragma unroll
  for (int kk = 0; kk < 4; kk++) {
    int dy = kk >> 1, dx = kk & 1;
    int ii = i0 + dy, jj = j0 + dx;
    m[kk] = (ii <= 13 && jj <= 13) ? 1.f : 0.f;
    int iic = ii > 13 ? 13 : ii, jjc = jj > 13 ? 13 : jj;
    rb[kk] = (iic * 14 + jjc) * 36;
  }
  for (int i = t; i < 2304; i += 256) cwm[i] = conv_w[i] * m[i & 3];
  __syncthreads();

  f32x4 acc[16];
#pragma unroll
  for (int o = 0; o < 16; o++) acc[o] = (f32x4){0.f, 0.f, 0.f, 0.f};
  const int kc4 = t * 4;  // this thread's 4 kcols
#pragma unroll 2
  for (int c = 0; c < 36; c++) {
    f32x4 f0 = *(const f32x4*)(fc_w + (rb[0] + c) * 1024 + kc4);
    f32x4 f1 = *(const f32x4*)(fc_w + (rb[1] + c) * 1024 + kc4);
    f32x4 f2 = *(const f32x4*)(fc_w + (rb[2] + c) * 1024 + kc4);
    f32x4 f3 = *(const f32x4*)(fc_w + (rb[3] + c) * 1024 + kc4);
#pragma unroll
    for (int o = 0; o < 16; o++) {
      f32x4 wv = *(const f32x4*)(cwm + (o * 36 + c) * 4);
      acc[o] += wv.x * f0 + wv.y * f1 + wv.z * f2 + wv.w * f3;
    }
  }
#pragma unroll
  for (int o = 0; o < 16; o++) {
    int n = o * 196 + i0 * 14 + j0;
    union { unsigned short s[4]; uint2 v; } u;
    u.s[0] = f2bf(acc[o][0]); u.s[1] = f2bf(acc[o][1]);
    u.s[2] = f2bf(acc[o][2]); u.s[3] = f2bf(acc[o][3]);
    *(uint2*)(Wc + n * 1024 + kc4) = u.v;
  }
  if (t < 16) {
    int o = t;
    float b = conv_b[o];
    for (int c = 0; c < 36; c++)
      for (int dy = 0; dy < 2; dy++) {
        int ii = i0 + dy; if (ii > 13) continue;
        for (int dx = 0; dx < 2; dx++) {
          int jj = j0 + dx; if (jj > 13) continue;
          b += conv_w[(o * 36 + c) * 4 + dy * 2 + dx] * fc_b[(ii * 14 + jj) * 36 + c];
        }
      }
    bc[o * 196 + i0 * 14 + j0] = b;
  }
}

// --------------------------- K2: bf16 MFMA GEMM ----------------------------
// Frozen at the measured-best configuration (r5/r8: 139.2/139.0 µs):
// 128x128 tile, BK=32, 4 waves, plain 2-barrier single-buffer loop,
// XCD-bijective swizzle, fused BN stats. All scheduling variants measured
// worse or neutral (drain-0 dbuf r3, BK=64 r6, 256² r4/r9, counted-vmcnt r11).
__global__ __launch_bounds__(256, 4) void k_gemm(const unsigned short* __restrict__ Xb,
                                                 const unsigned short* __restrict__ Wcb,
                                                 const float* __restrict__ bc,
                                                 unsigned short* __restrict__ h2,
                                                 float* __restrict__ stats) {
  __shared__ __align__(16) char lds[16384];  // A: [0,8K), B: [8K,16K)
  __shared__ float red[4][4];
  const int t = threadIdx.x;
  const int w = t >> 6, lane = t & 63;
  const int quad = lane >> 4, l15 = lane & 15;
  // XCD-bijective swizzle: bid <-> (xcd, mloc, nblk); 1600 = 8 x 8 x 25
  const int bid = blockIdx.x;
  const int xcd = bid & 7, j = bid >> 3;       // j in [0,200)
  const int mblk = xcd * 8 + (j & 7);          // [0,64)
  const int nblk = j >> 3;                     // [0,25)
  const int m0 = mblk * 128, n0 = nblk * 128;
  const int mrow = t & 127, tko = t >> 7;      // staging: row in tile, base ko
  const unsigned short* ga = Xb + (m0 + mrow) * 1024 + tko * 8;
  const unsigned short* gb = Wcb + (n0 + mrow) * 1024 + tko * 8;
  char* lA = lds;
  char* lB = lds + 8192;
  const int wbase = w * 1024;
  const int wm0 = (w >> 1) * 64, wn0 = (w & 1) * 64;

  f32x4 acc[4][4];
#pragma unroll
  for (int a = 0; a < 4; a++)
#pragma unroll
    for (int b = 0; b < 4; b++) acc[a][b] = (f32x4){0.f, 0.f, 0.f, 0.f};

  for (int kb = 0; kb < 1024; kb += 32) {
    __syncthreads();
    load16_to_lds(ga + kb,      lA + wbase);           // A slots ko = tko
    load16_to_lds(ga + kb + 16, lA + 4096 + wbase);    // A slots ko = 2+tko
    load16_to_lds(gb + kb,      lB + wbase);
    load16_to_lds(gb + kb + 16, lB + 4096 + wbase);
    __syncthreads();  // compiler emits s_waitcnt vmcnt(0) before s_barrier

    bf16x8 af[4], bfr[4];
#pragma unroll
    for (int mb = 0; mb < 4; mb++)
      af[mb] = *(const bf16x8*)(lA + quad * 2048 + (wm0 + mb * 16 + l15) * 16);
#pragma unroll
    for (int nb = 0; nb < 4; nb++)
      bfr[nb] = *(const bf16x8*)(lB + quad * 2048 + (wn0 + nb * 16 + l15) * 16);
#pragma unroll
    for (int mb = 0; mb < 4; mb++)
#pragma unroll
      for (int nb = 0; nb < 4; nb++)
        acc[mb][nb] = __builtin_amdgcn_mfma_f32_16x16x32_bf16(af[mb], bfr[nb], acc[mb][nb], 0, 0, 0);
  }

  // ---- epilogue: bias + leaky + bf16 store + fused BN partial sums ----
  const int cLo = n0 / 196;              // block spans channels cLo..cHi (cHi<=cLo+1)
  const int cHi = (n0 + 127) / 196;      // may be 16 for the padded tail block
  float ss0 = 0.f, ss1 = 0.f, sq0 = 0.f, sq1 = 0.f;
#pragma unroll
  for (int nb = 0; nb < 4; nb++) {
    int col = n0 + wn0 + nb * 16 + l15;
    float bias = bc[col];
    int ch = col / 196;
    bool hi = (ch != cLo);
    bool valid = col < 3136;
    float cs = 0.f, cq = 0.f;
#pragma unroll
    for (int mb = 0; mb < 4; mb++) {
#pragma unroll
      for (int r = 0; r < 4; r++) {
        int row = m0 + wm0 + mb * 16 + quad * 4 + r;  // C/D: row=(lane>>4)*4+reg, col=lane&15
        float v = leaky(acc[mb][nb][r] + bias);
        h2[row * 3200 + col] = f2bf(v);
        cs += v; cq += v * v;
      }
    }
    if (valid) {
      if (hi) { ss1 += cs; sq1 += cq; } else { ss0 += cs; sq0 += cq; }
    }
  }
#pragma unroll
  for (int off = 1; off < 64; off <<= 1) {
    ss0 += __shfl_xor(ss0, off, 64);
    ss1 += __shfl_xor(ss1, off, 64);
    sq0 += __shfl_xor(sq0, off, 64);
    sq1 += __shfl_xor(sq1, off, 64);
  }
  if (lane == 0) { red[w][0] = ss0; red[w][1] = ss1; red[w][2] = sq0; red[w][3] = sq1; }
  __syncthreads();
  if (t == 0) {
    float a0 = red[0][0] + red[1][0] + red[2][0] + red[3][0];
    float a1 = red[0][1] + red[1][1] + red[2][1] + red[3][1];
    float b0 = red[0][2] + red[1][2] + red[2][2] + red[3][2];
    float b1 = red[0][3] + red[1][3] + red[2][3] + red[3][3];
    atomicAdd(&stats[cLo], a0);
    atomicAdd(&stats[16 + cLo], b0);
    if (cHi != cLo && cHi < 16) {
      atomicAdd(&stats[cHi], a1);
      atomicAdd(&stats[16 + cHi], b1);
    }
  }
}

// ------------- K4: BN-apply + local conv1 + leaky + local conv2 ------------
// r8 measured-good structure (implied ~70 µs): 4 rows/block, h3 LDS staging
// (coalesced global reads, BN applied once), conv1 row-paired. The r12
// direct-global variant (no h3) measured 173 µs — scattered 28B gathers.
__global__ __launch_bounds__(256) void k_tail(const unsigned short* __restrict__ h2,
                                              const float* __restrict__ stats,
                                              const float* __restrict__ gamma,
                                              const float* __restrict__ beta,
                                              const float* __restrict__ lw1,
                                              const float* __restrict__ lw2,
                                              float* __restrict__ out) {
  __shared__ unsigned short h3[4 * 3138];  // bb stride 3138
  __shared__ float h4[4 * 1015];           // bb stride 1015
  __shared__ float sc[16], sh[16];
  int b0 = blockIdx.x * 4, t = threadIdx.x;
  if (t < 16) {
    const float inv = 1.f / 1605632.f;  // 8192*196
    float mean = stats[t] * inv;
    float var = stats[16 + t] * inv - mean * mean;
    float rstd = rsqrtf(var + 1e-5f);
    float s = gamma[t] * rstd;
    sc[t] = s; sh[t] = beta[t] - mean * s;
  }
  __syncthreads();
  // stage BN-applied h3 into LDS (bf16)
  for (int i = t; i < 6272; i += 256) {    // 4 rows * 1568 uints
    int bb = i / 1568, q = i - bb * 1568;
    int n = q * 2, o = n / 196;            // pair never straddles a channel (196 even)
    unsigned int u = *(const unsigned int*)(h2 + (b0 + bb) * 3200 + n);
    float v0 = bfbits2f(u & 0xffffu) * sc[o] + sh[o];
    float v1 = bfbits2f(u >> 16) * sc[o] + sh[o];
    unsigned int pk = (unsigned int)f2bf(v0) | ((unsigned int)f2bf(v1) << 16);
    *(unsigned int*)(h3 + bb * 3138 + n) = pk;
  }
  __syncthreads();
  // local conv 1: unit = (rp, o, y); rp picks rows {2rp, 2rp+1};
  // one float4 weight stream serves both rows.
  for (int u = t; u < 156; u += 256) {
    int rp = u & 1, rest = u >> 1;
    int o = rest / 13, y = rest - o * 13;
    int rA = 2 * rp, rB = 2 * rp + 1;
    float acc0[13], acc1[13];
#pragma unroll
    for (int x = 0; x < 13; x++) { acc0[x] = 0.f; acc1[x] = 0.f; }
    const unsigned short* hA = h3 + rA * 3138;
    const unsigned short* hB = h3 + rB * 3138;
    for (int c = 0; c < 16; c++) {
      float a0[14], a1[14], e0[14], e1[14];
      const unsigned int* pA0 = (const unsigned int*)(hA + c * 196 + y * 14);
      const unsigned int* pA1 = (const unsigned int*)(hA + c * 196 + (y + 1) * 14);
      const unsigned int* pB0 = (const unsigned int*)(hB + c * 196 + y * 14);
      const unsigned int* pB1 = (const unsigned int*)(hB + c * 196 + (y + 1) * 14);
#pragma unroll
      for (int q = 0; q < 7; q++) {
        unsigned int vA0 = pA0[q], vA1 = pA1[q], vB0 = pB0[q], vB1 = pB1[q];
        a0[2 * q] = bfbits2f(vA0 & 0xffffu); a0[2 * q + 1] = bfbits2f(vA0 >> 16);
        a1[2 * q] = bfbits2f(vA1 & 0xffffu); a1[2 * q + 1] = bfbits2f(vA1 >> 16);
        e0[2 * q] = bfbits2f(vB0 & 0xffffu); e0[2 * q + 1] = bfbits2f(vB0 >> 16);
        e1[2 * q] = bfbits2f(vB1 & 0xffffu); e1[2 * q + 1] = bfbits2f(vB1 >> 16);
      }
      const float4* wp4 = (const float4*)(lw1 + (((o * 16 + c) * 13 + y) * 13) * 4);
#pragma unroll
      for (int x = 0; x < 13; x++) {
        float4 wv = wp4[x];
        acc0[x] += a0[x] * wv.x + a0[x + 1] * wv.y + a1[x] * wv.z + a1[x + 1] * wv.w;
        acc1[x] += e0[x] * wv.x + e0[x + 1] * wv.y + e1[x] * wv.z + e1[x + 1] * wv.w;
      }
    }
#pragma unroll
    for (int x = 0; x < 13; x++) {
      h4[rA * 1015 + (o * 13 + y) * 13 + x] = leaky(acc0[x]);
      h4[rB * 1015 + (o * 13 + y) * 13 + x] = leaky(acc1[x]);
    }
  }
  __syncthreads();
  // local conv 2: 4*144 outputs, 24 MACs each (float4 weights)
  for (int oi = t; oi < 576; oi += 256) {
    int pos = oi >> 2, bb = oi & 3;
    int y = pos / 12, x = pos - y * 12;
    float a = 0.f;
    const float* hp = h4 + bb * 1015;
    const float4* w4 = (const float4*)lw2;
#pragma unroll
    for (int c = 0; c < 6; c++) {
      float4 wv = w4[(c * 12 + y) * 12 + x];
      int hb = c * 169 + y * 13 + x;
      a += hp[hb] * wv.x + hp[hb + 1] * wv.y +
           hp[hb + 13] * wv.z + hp[hb + 14] * wv.w;
    }
    out[(b0 + bb) * 144 + pos] = a;
  }
}

// ---------------------------------------------------------------------------
extern "C" void kernel_launch(void* const* d_in, const int* in_sizes, int n_in,
                              void* d_out, int out_size, void* d_ws, size_t ws_size,
                              hipStream_t stream) {
  const float* x      = (const float*)d_in[0];
  const float* fc_w   = (const float*)d_in[1];
  const float* fc_b   = (const float*)d_in[2];
  const float* conv_w = (const float*)d_in[3];
  const float* conv_b = (const float*)d_in[4];
  const float* gamma  = (const float*)d_in[5];
  const float* beta   = (const float*)d_in[6];
  const float* lw1    = (const float*)d_in[7];
  const float* lw2    = (const float*)d_in[8];

  char* ws = (char*)d_ws;
  // workspace layout (75.8 MB total)
  unsigned short* Xb    = (unsigned short*)(ws);                // 16,777,216 B
  unsigned short* Wc    = (unsigned short*)(ws + 16777216);     //  6,553,600 B
  float*          bc    = (float*)(ws + 23330816);              //     12,800 B
  float*          stats = (float*)(ws + 23343616);              //        128 B
  unsigned short* h2    = (unsigned short*)(ws + 23343744);     // 52,428,800 B

  k_cast_x<<<4096, 256, 0, stream>>>(x, Xb, stats);
  k_fold<<<197, 256, 0, stream>>>(fc_w, fc_b, conv_w, conv_b, Wc, bc);
  k_gemm<<<1600, 256, 0, stream>>>(Xb, Wc, bc, h2, stats);
  k_tail<<<2048, 256, 0, stream>>>(h2, stats, gamma, beta, lw1, lw2, (float*)d_out);
}